// Round 6
// baseline (391.845 us; speedup 1.0000x reference)
//
#include <hip/hip_runtime.h>
#include <stdint.h>

// Problem constants (from reference): B=8, L=4096, D=1024, S=255
constexpr int kB = 8;
constexpr int kL = 4096;
constexpr int kD = 1024;
constexpr int kS = 255;
constexpr int kM = kB * kL;   // 32768 rows of A / out
constexpr int kK = 2 * kD;    // 2048 reduction dim
constexpr int kN = kD;        // 1024 output features

typedef __bf16 bf16x8 __attribute__((ext_vector_type(8)));
typedef float  f32x4  __attribute__((ext_vector_type(4)));

// ---- workspace layout (bytes): full bf16 mirror (R2 layout) ----
constexpr size_t WS_WORDS = 0;                                   // 67,108,864 B bf16
constexpr size_t WS_SENTS = WS_WORDS + (size_t)kM * kD * 2;
constexpr size_t WS_W     = WS_SENTS + (size_t)kB * kS * kD * 2; // +4,177,920
constexpr size_t WS_ZP    = WS_W + (size_t)kN * kK * 2;          // +4,194,304
constexpr size_t WS_NEED  = WS_ZP + 3072;                        // zero page 3 KiB

// fp32 pair -> packed bf16x2, round-half-up (validated R0-R5)
__device__ __forceinline__ uint32_t pk_bf16x2(float a, float b) {
    uint32_t ua = __float_as_uint(a) + 0x8000u;
    uint32_t ub = __float_as_uint(b) + 0x8000u;
    return __builtin_amdgcn_perm(ub, ua, 0x07060302u);
}

// async global->LDS 16B per lane: dest = wave-uniform base + lane*16
__device__ __forceinline__ void async16(const void* g, void* l) {
    __builtin_amdgcn_global_load_lds(
        (const __attribute__((address_space(1))) uint32_t*)g,
        (__attribute__((address_space(3))) uint32_t*)l, 16, 0, 0);
}

#define WAITVM(n)  asm volatile("s_waitcnt vmcnt(" #n ")" ::: "memory")
#define WAITLGKM0  asm volatile("s_waitcnt lgkmcnt(0)" ::: "memory")

__device__ __forceinline__ void blockbar() {
    __builtin_amdgcn_sched_barrier(0);
    __builtin_amdgcn_s_barrier();
    __builtin_amdgcn_sched_barrier(0);
}

// ===================== prepass (R2-proven): fp32 -> bf16, grid-stride =======
__global__ __launch_bounds__(256)
void cvt_prepass2(const float4* __restrict__ words, const float4* __restrict__ sents,
                  const float4* __restrict__ W,
                  uint4* __restrict__ wordsB, uint4* __restrict__ sentsB,
                  uint4* __restrict__ WB, uint32_t* __restrict__ zp)
{
    constexpr size_t NW8 = (size_t)kM * kD / 8;       // 4,194,304
    constexpr size_t NS8 = (size_t)kB * kS * kD / 8;  //   261,120
    constexpr size_t NB8 = (size_t)kN * kK / 8;       //   262,144
    constexpr size_t NT8 = NW8 + NS8 + NB8;
    if (blockIdx.x == 0) {                            // zero page for invalid rows
        for (int t = threadIdx.x; t < 768; t += 256) zp[t] = 0u;
    }
    const size_t stride = (size_t)gridDim.x * blockDim.x;
    for (size_t i = (size_t)blockIdx.x * blockDim.x + threadIdx.x; i < NT8; i += stride) {
        const float4* src; uint4* dst; size_t j;
        if (i < NW8)            { src = words; dst = wordsB; j = i; }
        else if (i < NW8 + NS8) { src = sents; dst = sentsB; j = i - NW8; }
        else                    { src = W;     dst = WB;     j = i - NW8 - NS8; }
        float4 a  = src[2 * j];
        float4 b2 = src[2 * j + 1];
        uint4 o;
        o.x = pk_bf16x2(a.x,  a.y);
        o.y = pk_bf16x2(a.z,  a.w);
        o.z = pk_bf16x2(b2.x, b2.y);
        o.w = pk_bf16x2(b2.z, b2.w);
        dst[j] = o;
    }
}

// ===================== GEMM v6: frag-linear LDS + 8-phase interleave ========
// C[m,n] = relu( sum_k A[m,k]*W[n,k] + bias[n] )
// 256x256 tile, BK=64, 8 waves (2Mx4N, wave 128x64), 2x64KB ping-pong LDS.
// FRAG-LINEAR LDS LAYOUT: region = [slab(16 rows)][kchunk 0..7][fr 0..15][16B]
// where kchunk = ks*4+quad. A fragment ds_read_b128 is then base + lane*16 —
// 1024 B contiguous per wave, conflict-free (vs 8 lanes/16B-slot for ANY
// row-major layout with stride%128B==0; XOR swizzles cannot fix that).
// Staging: global_load_lds writes linearly; the per-lane GLOBAL source is the
// inverse mapping (row = j*64 + (tid>>7)*16 + (tid&15), col = ((tid>>4)&7)*16)
// — pure pointer setup, identical lane->(row,k) frag semantics as v5 (verified).
// Schedule per K-tile: 4 phases x {ds_read, stage, bar, lgkm0, schedbar,
// setprio(1), 16 MFMA, setprio(0), bar}. Stages: A(t+1) at p1, B(t+1) at p2.
// Only vmem drain: WAITVM(0) after p4's MFMA (~2.5 phases after issue => ~free),
// + barrier => cross-wave data-ready for t+1's p1 reads. Overwrite safety:
// parity^1's last ds_reads (t-1.p3 ag) drained at t-1.p3's lgkm0, >=2 barriers
// before t.p1's DMA issue.
__global__ __launch_bounds__(512, 2)
void wsib_gemm_v6(const uint8_t* __restrict__ wordsB,   // [32768][1024] bf16
                  const uint8_t* __restrict__ sentsB,   // [8*255][1024] bf16
                  const uint8_t* __restrict__ WB,       // [1024][2048]  bf16
                  const float*   __restrict__ bias,
                  const int*     __restrict__ smap,
                  const uint8_t* __restrict__ zp,
                  float* __restrict__ out)
{
    __shared__ uint8_t lds[2][2][32768];   // [parity][A=0/B=1][32 KiB]

    const int tid  = threadIdx.x;
    const int w    = tid >> 6;           // wave 0..7
    const int lane = tid & 63;
    const int nT = blockIdx.x;           // 0..3
    const int mT = blockIdx.y;           // 0..127

    const int wm = (w >> 2) * 128;       // 0 or 128
    const int wn = (w & 3) * 64;         // 0,64,128,192
    const int fr = lane & 15, quad = lane >> 4;
    const int lo = lane * 16;            // frag-linear lane offset
    const int slabA = wm >> 4;           // 0 or 8
    const int slabB = wn >> 4;           // 0,4,8,12

    float bv[4];
    #pragma unroll
    for (int ni = 0; ni < 4; ++ni) bv[ni] = bias[nT * 256 + wn + ni * 16 + fr];

    // ---- staging source pointers (per lane, frag-linear inverse mapping) ----
    // load j of a region covers phys = j*8192 + tid*16 ->
    //   slab = j*4 + (tid>>7), kchunk = (tid>>4)&7, fr = tid&15
    //   row = j*64 + (tid>>7)*16 + (tid&15), colbyte = ((tid>>4)&7)*16
    const int rb   = ((tid >> 7) << 4) + (tid & 15);   // 0..63
    const int colb = ((tid >> 4) & 7) * 16;            // 0..112
    const uint8_t* pAW[4]; const uint8_t* pAS[4]; const uint8_t* pB[4];
    const int bIdx = (mT * 256) >> 12;   // tile never crosses batch (4096%256==0)
    #pragma unroll
    for (int j = 0; j < 4; ++j) {
        const int rA = mT * 256 + rb + j * 64;
        pAW[j] = wordsB + (size_t)rA * 2048 + colb;
        const int s = smap[rA];
        pAS[j] = (s >= 0) ? sentsB + (size_t)(bIdx * kS + s) * 2048 + colb : zp + colb;
        pB[j]  = WB + (size_t)(nT * 256 + rb + j * 64) * 4096 + colb;
    }

    auto stageA = [&](int tn) {          // tile tn -> parity tn&1, 4 loads
        uint8_t* SA = (uint8_t*)lds[tn & 1][0];
        #pragma unroll
        for (int j = 0; j < 4; ++j) {
            const uint8_t* s = (tn < 16) ? pAW[j] + tn * 128 : pAS[j] + (tn - 16) * 128;
            async16(s, SA + j * 8192 + w * 1024);
        }
    };
    auto stageB = [&](int tn) {
        uint8_t* SB = (uint8_t*)lds[tn & 1][1];
        #pragma unroll
        for (int j = 0; j < 4; ++j)
            async16(pB[j] + tn * 128, SB + j * 8192 + w * 1024);
    };

    f32x4 acc[8][4];
    #pragma unroll
    for (int i = 0; i < 8; ++i)
        #pragma unroll
        for (int j = 0; j < 4; ++j) acc[i][j] = (f32x4){0.f, 0.f, 0.f, 0.f};

    // ---- prologue: stage tile 0 into parity 0, drain, publish ----
    stageA(0);
    stageB(0);
    WAITVM(0);
    blockbar();

    bf16x8 af[4][2], bf0[2][2], bf1[2][2];

    // ---- main loop: 32 K-tiles of 64, 4 phases each ----
    #pragma unroll 1
    for (int kt = 0; kt < 32; ++kt) {
        const int P = kt & 1;
        uint8_t* Ab = (uint8_t*)lds[P][0];
        uint8_t* Bb = (uint8_t*)lds[P][1];
        const int tn = kt + 1;

        // ---------- phase 1: af(slabs 0-3) + bf0, stage A(t+1), Q(0,0) ------
        #pragma unroll
        for (int mi = 0; mi < 4; ++mi)
            #pragma unroll
            for (int ks = 0; ks < 2; ++ks)
                af[mi][ks] = *(const bf16x8*)(Ab + (slabA + mi) * 2048 + ks * 1024 + lo);
        #pragma unroll
        for (int ni = 0; ni < 2; ++ni)
            #pragma unroll
            for (int ks = 0; ks < 2; ++ks)
                bf0[ni][ks] = *(const bf16x8*)(Bb + (slabB + ni) * 2048 + ks * 1024 + lo);
        if (kt < 31) stageA(tn);
        blockbar();
        WAITLGKM0;
        __builtin_amdgcn_sched_barrier(0);
        __builtin_amdgcn_s_setprio(1);
        #pragma unroll
        for (int ks = 0; ks < 2; ++ks)
            #pragma unroll
            for (int mi = 0; mi < 4; ++mi)
                #pragma unroll
                for (int ni = 0; ni < 2; ++ni)
                    acc[mi][ni] = __builtin_amdgcn_mfma_f32_16x16x32_bf16(
                        af[mi][ks], bf0[ni][ks], acc[mi][ni], 0, 0, 0);
        __builtin_amdgcn_s_setprio(0);
        blockbar();

        // ---------- phase 2: bf1, stage B(t+1), Q(0,1) ----------------------
        #pragma unroll
        for (int ni = 0; ni < 2; ++ni)
            #pragma unroll
            for (int ks = 0; ks < 2; ++ks)
                bf1[ni][ks] = *(const bf16x8*)(Bb + (slabB + 2 + ni) * 2048 + ks * 1024 + lo);
        if (kt < 31) stageB(tn);
        blockbar();
        WAITLGKM0;
        __builtin_amdgcn_sched_barrier(0);
        __builtin_amdgcn_s_setprio(1);
        #pragma unroll
        for (int ks = 0; ks < 2; ++ks)
            #pragma unroll
            for (int mi = 0; mi < 4; ++mi)
                #pragma unroll
                for (int ni = 0; ni < 2; ++ni)
                    acc[mi][ni + 2] = __builtin_amdgcn_mfma_f32_16x16x32_bf16(
                        af[mi][ks], bf1[ni][ks], acc[mi][ni + 2], 0, 0, 0);
        __builtin_amdgcn_s_setprio(0);
        blockbar();

        // ---------- phase 3: af(slabs 4-7), Q(1,0) --------------------------
        #pragma unroll
        for (int mi = 0; mi < 4; ++mi)
            #pragma unroll
            for (int ks = 0; ks < 2; ++ks)
                af[mi][ks] = *(const bf16x8*)(Ab + (slabA + 4 + mi) * 2048 + ks * 1024 + lo);
        blockbar();
        WAITLGKM0;
        __builtin_amdgcn_sched_barrier(0);
        __builtin_amdgcn_s_setprio(1);
        #pragma unroll
        for (int ks = 0; ks < 2; ++ks)
            #pragma unroll
            for (int mi = 0; mi < 4; ++mi)
                #pragma unroll
                for (int ni = 0; ni < 2; ++ni)
                    acc[mi + 4][ni] = __builtin_amdgcn_mfma_f32_16x16x32_bf16(
                        af[mi][ks], bf0[ni][ks], acc[mi + 4][ni], 0, 0, 0);
        __builtin_amdgcn_s_setprio(0);
        blockbar();

        // ---------- phase 4: Q(1,1), drain t+1's stages, publish ------------
        __builtin_amdgcn_s_setprio(1);
        #pragma unroll
        for (int ks = 0; ks < 2; ++ks)
            #pragma unroll
            for (int mi = 0; mi < 4; ++mi)
                #pragma unroll
                for (int ni = 0; ni < 2; ++ni)
                    acc[mi + 4][ni + 2] = __builtin_amdgcn_mfma_f32_16x16x32_bf16(
                        af[mi][ks], bf1[ni][ks], acc[mi + 4][ni + 2], 0, 0, 0);
        __builtin_amdgcn_s_setprio(0);
        WAITVM(0);   // t+1's 8 loads issued 2-3 phases ago -> near-free drain
        blockbar();
    }

    // ---- epilogue: bias + relu, fp32 store ----
    // C/D layout (verified): col = lane&15, row = quad*4 + r
    const int rowBase = mT * 256 + wm + quad * 4;
    const int colBase = nT * 256 + wn + fr;
    #pragma unroll
    for (int mi = 0; mi < 8; ++mi) {
        #pragma unroll
        for (int ni = 0; ni < 4; ++ni) {
            const int col = colBase + ni * 16;
            #pragma unroll
            for (int r = 0; r < 4; ++r) {
                const int row = rowBase + mi * 16 + r;
                out[(size_t)row * kN + col] = fmaxf(acc[mi][ni][r] + bv[ni], 0.f);
            }
        }
    }
}

// ===================== fallback (R2 kernel, no-workspace path) ==============
#define TILE_M 128
#define TILE_N 128
#define TILE_K 32
#define LDS_STRIDE 20
__global__ __launch_bounds__(256)
void wsib_gemm_fb(const float* __restrict__ words, const float* __restrict__ sents,
                  const float* __restrict__ W, const float* __restrict__ bias,
                  const int* __restrict__ smap, float* __restrict__ out)
{
    __shared__ uint32_t Asm[TILE_M * LDS_STRIDE];
    __shared__ uint32_t Bsm[TILE_N * LDS_STRIDE];
    const int tid = threadIdx.x, nT = blockIdx.x, mT = blockIdx.y;
    const int sRow = tid >> 1, half = tid & 1;
    const int mRow = mT * TILE_M + sRow, bIdx = mRow >> 12;
    const float* wsrc = words + (size_t)mRow * kD + half * 16;
    const int sidx = smap[mRow];
    const float* ssrc = (sidx >= 0) ? sents + ((size_t)bIdx * kS + sidx) * kD + half * 16 : nullptr;
    const float* bsrc = W + (size_t)(nT * TILE_N + sRow) * kK + half * 16;
    uint32_t* adst = &Asm[sRow * LDS_STRIDE + half * 8];
    uint32_t* bdst = &Bsm[sRow * LDS_STRIDE + half * 8];
    const int lane = tid & 63, wv = tid >> 6;
    const int wm = (wv & 1) * 64, wn = (wv >> 1) * 64;
    const int fr = lane & 15, quad = lane >> 4;
    f32x4 acc[4][4];
    #pragma unroll
    for (int i = 0; i < 4; ++i)
        #pragma unroll
        for (int j = 0; j < 4; ++j) acc[i][j] = (f32x4){0.f, 0.f, 0.f, 0.f};
    float4 ra[4], rb[4];
    {
        const float4* pa = (const float4*)wsrc; const float4* pb = (const float4*)bsrc;
        #pragma unroll
        for (int i = 0; i < 4; ++i) { ra[i] = pa[i]; rb[i] = pb[i]; }
    }
    for (int k0 = 0; k0 < kK; k0 += TILE_K) {
        uint32_t pa[8], pb[8];
        #pragma unroll
        for (int i = 0; i < 4; ++i) {
            pa[2*i] = pk_bf16x2(ra[i].x, ra[i].y); pa[2*i+1] = pk_bf16x2(ra[i].z, ra[i].w);
            pb[2*i] = pk_bf16x2(rb[i].x, rb[i].y); pb[2*i+1] = pk_bf16x2(rb[i].z, rb[i].w);
        }
        __syncthreads();
        ((uint4*)adst)[0] = make_uint4(pa[0], pa[1], pa[2], pa[3]);
        ((uint4*)adst)[1] = make_uint4(pa[4], pa[5], pa[6], pa[7]);
        ((uint4*)bdst)[0] = make_uint4(pb[0], pb[1], pb[2], pb[3]);
        ((uint4*)bdst)[1] = make_uint4(pb[4], pb[5], pb[6], pb[7]);
        __syncthreads();
        const int k1 = k0 + TILE_K;
        if (k1 < kK) {
            const float* asrc = (k1 < kD) ? (wsrc + k1) : (ssrc ? (ssrc + (k1 - kD)) : nullptr);
            if (asrc) { const float4* p = (const float4*)asrc;
                #pragma unroll
                for (int i = 0; i < 4; ++i) ra[i] = p[i];
            } else {
                #pragma unroll
                for (int i = 0; i < 4; ++i) ra[i] = make_float4(0.f, 0.f, 0.f, 0.f);
            }
            const float4* p = (const float4*)(bsrc + k1);
            #pragma unroll
            for (int i = 0; i < 4; ++i) rb[i] = p[i];
        }
        bf16x8 af[4], bfv[4];
        #pragma unroll
        for (int mi = 0; mi < 4; ++mi)
            af[mi] = *(const bf16x8*)&Asm[(wm + mi * 16 + fr) * LDS_STRIDE + quad * 4];
        #pragma unroll
        for (int ni = 0; ni < 4; ++ni)
            bfv[ni] = *(const bf16x8*)&Bsm[(wn + ni * 16 + fr) * LDS_STRIDE + quad * 4];
        #pragma unroll
        for (int mi = 0; mi < 4; ++mi)
            #pragma unroll
            for (int ni = 0; ni < 4; ++ni)
                acc[mi][ni] = __builtin_amdgcn_mfma_f32_16x16x32_bf16(af[mi], bfv[ni], acc[mi][ni], 0, 0, 0);
    }
    const int rowBase = mT * TILE_M + wm, colBase = nT * TILE_N + wn;
    float bv[4];
    #pragma unroll
    for (int ni = 0; ni < 4; ++ni) bv[ni] = bias[colBase + ni * 16 + fr];
    #pragma unroll
    for (int mi = 0; mi < 4; ++mi)
        #pragma unroll
        for (int ni = 0; ni < 4; ++ni) {
            const int col = colBase + ni * 16 + fr;
            #pragma unroll
            for (int r = 0; r < 4; ++r) {
                const int row = rowBase + mi * 16 + quad * 4 + r;
                out[(size_t)row * kN + col] = fmaxf(acc[mi][ni][r] + bv[ni], 0.f);
            }
        }
}

extern "C" void kernel_launch(void* const* d_in, const int* in_sizes, int n_in,
                              void* d_out, int out_size, void* d_ws, size_t ws_size,
                              hipStream_t stream) {
    const float* words = (const float*)d_in[0];   // [8, 4096, 1024] f32
    const float* sents = (const float*)d_in[1];   // [8, 255, 1024]  f32
    const float* W     = (const float*)d_in[2];   // [1024, 2048]    f32
    const float* bias  = (const float*)d_in[3];   // [1024]          f32
    const int*   smap  = (const int*)d_in[4];     // [8, 4096]       i32
    float* out = (float*)d_out;                   // [8, 4096, 1024] f32

    if (ws_size >= WS_NEED) {
        uint8_t* ws = (uint8_t*)d_ws;
        uint4* wordsB = (uint4*)(ws + WS_WORDS);
        uint4* sentsB = (uint4*)(ws + WS_SENTS);
        uint4* WB     = (uint4*)(ws + WS_W);
        uint32_t* zp  = (uint32_t*)(ws + WS_ZP);
        cvt_prepass2<<<2048, 256, 0, stream>>>(
            (const float4*)words, (const float4*)sents, (const float4*)W,
            wordsB, sentsB, WB, zp);
        dim3 grid(kN / 256, kM / 256);            // (4, 128)
        wsib_gemm_v6<<<grid, 512, 0, stream>>>(
            (const uint8_t*)wordsB, (const uint8_t*)sentsB, (const uint8_t*)WB,
            bias, smap, (const uint8_t*)zp, out);
    } else {
        dim3 grid(kN / TILE_N, kM / TILE_M);
        wsib_gemm_fb<<<grid, 256, 0, stream>>>(words, sents, W, bias, smap, out);
    }
}

// Round 7
// 372.248 us; speedup vs baseline: 1.0526x; 1.0526x over previous
//
#include <hip/hip_runtime.h>
#include <stdint.h>

// Problem constants (from reference): B=8, L=4096, D=1024, S=255
constexpr int kB = 8;
constexpr int kL = 4096;
constexpr int kD = 1024;
constexpr int kS = 255;
constexpr int kM = kB * kL;   // 32768 rows of A / out
constexpr int kK = 2 * kD;    // 2048 reduction dim
constexpr int kN = kD;        // 1024 output features

typedef __bf16 bf16x8 __attribute__((ext_vector_type(8)));
typedef float  f32x4  __attribute__((ext_vector_type(4)));

// ---- workspace layout (bytes): full bf16 mirror (R2 layout) ----
constexpr size_t WS_WORDS = 0;                                   // 67,108,864 B bf16
constexpr size_t WS_SENTS = WS_WORDS + (size_t)kM * kD * 2;
constexpr size_t WS_W     = WS_SENTS + (size_t)kB * kS * kD * 2; // +4,177,920
constexpr size_t WS_ZP    = WS_W + (size_t)kN * kK * 2;          // +4,194,304
constexpr size_t WS_NEED  = WS_ZP + 3072;                        // zero page 3 KiB

// fp32 pair -> packed bf16x2, round-half-up (validated R0-R6)
__device__ __forceinline__ uint32_t pk_bf16x2(float a, float b) {
    uint32_t ua = __float_as_uint(a) + 0x8000u;
    uint32_t ub = __float_as_uint(b) + 0x8000u;
    return __builtin_amdgcn_perm(ub, ua, 0x07060302u);
}

// async global->LDS 16B per lane: dest = wave-uniform base + lane*16
__device__ __forceinline__ void async16(const void* g, void* l) {
    __builtin_amdgcn_global_load_lds(
        (const __attribute__((address_space(1))) uint32_t*)g,
        (__attribute__((address_space(3))) uint32_t*)l, 16, 0, 0);
}

#define WAITVM(n)  asm volatile("s_waitcnt vmcnt(" #n ")" ::: "memory")
#define WAITLGKM0  asm volatile("s_waitcnt lgkmcnt(0)" ::: "memory")

__device__ __forceinline__ void blockbar() {
    __builtin_amdgcn_sched_barrier(0);
    __builtin_amdgcn_s_barrier();
    __builtin_amdgcn_sched_barrier(0);
}

// ===================== prepass (R2-proven): fp32 -> bf16, grid-stride =======
__global__ __launch_bounds__(256)
void cvt_prepass2(const float4* __restrict__ words, const float4* __restrict__ sents,
                  const float4* __restrict__ W,
                  uint4* __restrict__ wordsB, uint4* __restrict__ sentsB,
                  uint4* __restrict__ WB, uint32_t* __restrict__ zp)
{
    constexpr size_t NW8 = (size_t)kM * kD / 8;       // 4,194,304
    constexpr size_t NS8 = (size_t)kB * kS * kD / 8;  //   261,120
    constexpr size_t NB8 = (size_t)kN * kK / 8;       //   262,144
    constexpr size_t NT8 = NW8 + NS8 + NB8;
    if (blockIdx.x == 0) {                            // zero page for invalid rows
        for (int t = threadIdx.x; t < 768; t += 256) zp[t] = 0u;
    }
    const size_t stride = (size_t)gridDim.x * blockDim.x;
    for (size_t i = (size_t)blockIdx.x * blockDim.x + threadIdx.x; i < NT8; i += stride) {
        const float4* src; uint4* dst; size_t j;
        if (i < NW8)            { src = words; dst = wordsB; j = i; }
        else if (i < NW8 + NS8) { src = sents; dst = sentsB; j = i - NW8; }
        else                    { src = W;     dst = WB;     j = i - NW8 - NS8; }
        float4 a  = src[2 * j];
        float4 b2 = src[2 * j + 1];
        uint4 o;
        o.x = pk_bf16x2(a.x,  a.y);
        o.y = pk_bf16x2(a.z,  a.w);
        o.z = pk_bf16x2(b2.x, b2.y);
        o.w = pk_bf16x2(b2.z, b2.w);
        dst[j] = o;
    }
}

// ===================== GEMM v7: v5 schedule + v6 frag-linear layout =========
// C[m,n] = relu( sum_k A[m,k]*W[n,k] + bias[n] )
// The T2+T4 CONJUNCTION test: v5's counted-vmcnt 1-barrier schedule (proven,
// 156us) with v6's conflict-free frag-linear LDS (proven, 0 conflicts).
// Layout per 16KB region (BK=32): [slab 0..15][quad 0..3][fr 0..15][16B];
// fragment ds_read_b128 = region + slab*1024 + lane*16 (1024B/wave, 0-conflict).
// Staging inverse map: load j (j=0,1) dest = region + j*8192 + (tid>>6)*1024
// + lane*16  ->  row = j*128 + w*16 + (lane&15), colbyte = (lane>>4)*16.
// Schedule, vmcnt ledger, lifetime proof: IDENTICAL to v5 (4 bufs, 1 barrier
// per K-step; WAITLGKM0 + WAITVM(4) at mid; drain 0 only t>=62).
__global__ __launch_bounds__(512, 2)
void wsib_gemm_v7(const uint8_t* __restrict__ wordsB,   // [32768][1024] bf16
                  const uint8_t* __restrict__ sentsB,   // [8*255][1024] bf16
                  const uint8_t* __restrict__ WB,       // [1024][2048]  bf16
                  const float*   __restrict__ bias,
                  const int*     __restrict__ smap,
                  const uint8_t* __restrict__ zp,
                  float* __restrict__ out)
{
    __shared__ uint8_t lds[4][2][16384];   // [buf][A=0/B=1][frag-linear 16KB]

    const int tid  = threadIdx.x;
    const int w    = tid >> 6;           // wave 0..7
    const int lane = tid & 63;
    const int nT = blockIdx.x;           // 0..3
    const int mT = blockIdx.y;           // 0..127

    const int wm = (w >> 2) * 128;       // 0 or 128
    const int wn = (w & 3) * 64;         // 0,64,128,192
    const int fr = lane & 15, quad = lane >> 4;
    const int lo = lane * 16;            // frag-linear lane offset
    const int slabA = (w >> 2) * 8;      // wm/16
    const int slabB = (w & 3) * 4;       // wn/16

    float bv[4];
    #pragma unroll
    for (int ni = 0; ni < 4; ++ni) bv[ni] = bias[nT * 256 + wn + ni * 16 + fr];

    // ---- staging source pointers (frag-linear inverse mapping) ----
    // thread covers rows r0 = w*16+fr (j=0) and r1 = r0+128 (j=1),
    // k-chunk byte = quad*16 within each 64-B (BK=32) k-slab.
    const int colb = quad * 16;
    const int r0 = w * 16 + fr, r1 = r0 + 128;
    const int gA0 = mT * 256 + r0, gA1 = mT * 256 + r1;
    const int bIdx = gA0 >> 12;               // tile never crosses batch
    const uint8_t* aw0 = wordsB + (size_t)gA0 * 2048 + colb;
    const uint8_t* aw1 = wordsB + (size_t)gA1 * 2048 + colb;
    const int s0 = smap[gA0], s1 = smap[gA1];
    const uint8_t* as0 = (s0 >= 0) ? sentsB + (size_t)(bIdx * kS + s0) * 2048 + colb : zp + colb;
    const uint8_t* as1 = (s1 >= 0) ? sentsB + (size_t)(bIdx * kS + s1) * 2048 + colb : zp + colb;
    const uint8_t* pB0 = WB + (size_t)(nT * 256 + r0) * 4096 + colb;
    const uint8_t* pB1 = WB + (size_t)(nT * 256 + r1) * 4096 + colb;

    auto stage = [&](int buf, int t) {   // 4 loads: A j0,j1; B j0,j1
        uint8_t* A  = (uint8_t*)lds[buf][0];
        uint8_t* Bb = (uint8_t*)lds[buf][1];
        const uint8_t* a0 = (t < 32) ? aw0 + t * 64 : as0 + (t - 32) * 64;
        const uint8_t* a1 = (t < 32) ? aw1 + t * 64 : as1 + (t - 32) * 64;
        async16(a0, A + w * 1024);
        async16(a1, A + 8192 + w * 1024);
        async16(pB0 + t * 64, Bb + w * 1024);
        async16(pB1 + t * 64, Bb + 8192 + w * 1024);
    };

    f32x4 acc[8][4];
    #pragma unroll
    for (int i = 0; i < 8; ++i)
        #pragma unroll
        for (int j = 0; j < 4; ++j) acc[i][j] = (f32x4){0.f, 0.f, 0.f, 0.f};

    // ---- prologue: stage tiles 0,1,2; tile 0 complete; prime frags(0) ----
    stage(0, 0);
    stage(1, 1);
    stage(2, 2);
    WAITVM(8);
    blockbar();

    bf16x8 af[4], bfA[4], bfB[4];
    #pragma unroll
    for (int mi = 0; mi < 4; ++mi)
        af[mi] = *(const bf16x8*)((uint8_t*)lds[0][0] + (slabA + mi) * 1024 + lo);
    #pragma unroll
    for (int ni = 0; ni < 4; ++ni)
        bfA[ni] = *(const bf16x8*)((uint8_t*)lds[0][1] + (slabB + ni) * 1024 + lo);

    // ---- main loop: 64 K-steps of 32, 1 barrier each (v5 schedule) ----
    auto kstep = [&](int t, bf16x8 (&bfc)[4], bf16x8 (&bfn)[4]) {
        uint8_t* bufT = (uint8_t*)lds[t & 3][0];

        // phase A: read ag(t) (slabs +4..+7), MFMA-A (acc rows 0..63)
        bf16x8 ag[4];
        #pragma unroll
        for (int mi = 0; mi < 4; ++mi)
            ag[mi] = *(const bf16x8*)(bufT + (slabA + 4 + mi) * 1024 + lo);
        __builtin_amdgcn_s_setprio(1);
        #pragma unroll
        for (int mi = 0; mi < 4; ++mi)
            #pragma unroll
            for (int ni = 0; ni < 4; ++ni)
                acc[mi][ni] = __builtin_amdgcn_mfma_f32_16x16x32_bf16(
                    af[mi], bfc[ni], acc[mi][ni], 0, 0, 0);
        __builtin_amdgcn_s_setprio(0);

        // mid: drain own ds_reads; tile t+1 DMA-complete; publish via barrier
        WAITLGKM0;
        if (t < 62) { WAITVM(4); } else { WAITVM(0); }
        blockbar();

        // phase B: issue DMA for tile t+3, read frags(t+1), MFMA-B
        if (t + 3 < 64) stage((t + 3) & 3, t + 3);
        if (t + 1 < 64) {
            uint8_t* bufNA = (uint8_t*)lds[(t + 1) & 3][0];
            uint8_t* bufNB = (uint8_t*)lds[(t + 1) & 3][1];
            #pragma unroll
            for (int ni = 0; ni < 4; ++ni)
                bfn[ni] = *(const bf16x8*)(bufNB + (slabB + ni) * 1024 + lo);
            #pragma unroll
            for (int mi = 0; mi < 4; ++mi)
                af[mi] = *(const bf16x8*)(bufNA + (slabA + mi) * 1024 + lo);
        }
        __builtin_amdgcn_s_setprio(1);
        #pragma unroll
        for (int mi = 0; mi < 4; ++mi)
            #pragma unroll
            for (int ni = 0; ni < 4; ++ni)
                acc[mi + 4][ni] = __builtin_amdgcn_mfma_f32_16x16x32_bf16(
                    ag[mi], bfc[ni], acc[mi + 4][ni], 0, 0, 0);
        __builtin_amdgcn_s_setprio(0);
    };

    #pragma unroll 1
    for (int t2 = 0; t2 < 32; ++t2) {
        kstep(2 * t2,     bfA, bfB);
        kstep(2 * t2 + 1, bfB, bfA);
    }

    // ---- epilogue: bias + relu, fp32 store ----
    // C/D layout (verified): col = lane&15, row = quad*4 + r
    const int rowBase = mT * 256 + wm + quad * 4;
    const int colBase = nT * 256 + wn + fr;
    #pragma unroll
    for (int mi = 0; mi < 8; ++mi) {
        #pragma unroll
        for (int ni = 0; ni < 4; ++ni) {
            const int col = colBase + ni * 16;
            #pragma unroll
            for (int r = 0; r < 4; ++r) {
                const int row = rowBase + mi * 16 + r;
                out[(size_t)row * kN + col] = fmaxf(acc[mi][ni][r] + bv[ni], 0.f);
            }
        }
    }
}

// ===================== fallback (R2 kernel, no-workspace path) ==============
#define TILE_M 128
#define TILE_N 128
#define TILE_K 32
#define LDS_STRIDE 20
__global__ __launch_bounds__(256)
void wsib_gemm_fb(const float* __restrict__ words, const float* __restrict__ sents,
                  const float* __restrict__ W, const float* __restrict__ bias,
                  const int* __restrict__ smap, float* __restrict__ out)
{
    __shared__ uint32_t Asm[TILE_M * LDS_STRIDE];
    __shared__ uint32_t Bsm[TILE_N * LDS_STRIDE];
    const int tid = threadIdx.x, nT = blockIdx.x, mT = blockIdx.y;
    const int sRow = tid >> 1, half = tid & 1;
    const int mRow = mT * TILE_M + sRow, bIdx = mRow >> 12;
    const float* wsrc = words + (size_t)mRow * kD + half * 16;
    const int sidx = smap[mRow];
    const float* ssrc = (sidx >= 0) ? sents + ((size_t)bIdx * kS + sidx) * kD + half * 16 : nullptr;
    const float* bsrc = W + (size_t)(nT * TILE_N + sRow) * kK + half * 16;
    uint32_t* adst = &Asm[sRow * LDS_STRIDE + half * 8];
    uint32_t* bdst = &Bsm[sRow * LDS_STRIDE + half * 8];
    const int lane = tid & 63, wv = tid >> 6;
    const int wm = (wv & 1) * 64, wn = (wv >> 1) * 64;
    const int fr = lane & 15, quad = lane >> 4;
    f32x4 acc[4][4];
    #pragma unroll
    for (int i = 0; i < 4; ++i)
        #pragma unroll
        for (int j = 0; j < 4; ++j) acc[i][j] = (f32x4){0.f, 0.f, 0.f, 0.f};
    float4 ra[4], rb[4];
    {
        const float4* pa = (const float4*)wsrc; const float4* pb = (const float4*)bsrc;
        #pragma unroll
        for (int i = 0; i < 4; ++i) { ra[i] = pa[i]; rb[i] = pb[i]; }
    }
    for (int k0 = 0; k0 < kK; k0 += TILE_K) {
        uint32_t pa[8], pb[8];
        #pragma unroll
        for (int i = 0; i < 4; ++i) {
            pa[2*i] = pk_bf16x2(ra[i].x, ra[i].y); pa[2*i+1] = pk_bf16x2(ra[i].z, ra[i].w);
            pb[2*i] = pk_bf16x2(rb[i].x, rb[i].y); pb[2*i+1] = pk_bf16x2(rb[i].z, rb[i].w);
        }
        __syncthreads();
        ((uint4*)adst)[0] = make_uint4(pa[0], pa[1], pa[2], pa[3]);
        ((uint4*)adst)[1] = make_uint4(pa[4], pa[5], pa[6], pa[7]);
        ((uint4*)bdst)[0] = make_uint4(pb[0], pb[1], pb[2], pb[3]);
        ((uint4*)bdst)[1] = make_uint4(pb[4], pb[5], pb[6], pb[7]);
        __syncthreads();
        const int k1 = k0 + TILE_K;
        if (k1 < kK) {
            const float* asrc = (k1 < kD) ? (wsrc + k1) : (ssrc ? (ssrc + (k1 - kD)) : nullptr);
            if (asrc) { const float4* p = (const float4*)asrc;
                #pragma unroll
                for (int i = 0; i < 4; ++i) ra[i] = p[i];
            } else {
                #pragma unroll
                for (int i = 0; i < 4; ++i) ra[i] = make_float4(0.f, 0.f, 0.f, 0.f);
            }
            const float4* p = (const float4*)(bsrc + k1);
            #pragma unroll
            for (int i = 0; i < 4; ++i) rb[i] = p[i];
        }
        bf16x8 af[4], bfv[4];
        #pragma unroll
        for (int mi = 0; mi < 4; ++mi)
            af[mi] = *(const bf16x8*)&Asm[(wm + mi * 16 + fr) * LDS_STRIDE + quad * 4];
        #pragma unroll
        for (int ni = 0; ni < 4; ++ni)
            bfv[ni] = *(const bf16x8*)&Bsm[(wn + ni * 16 + fr) * LDS_STRIDE + quad * 4];
        #pragma unroll
        for (int mi = 0; mi < 4; ++mi)
            #pragma unroll
            for (int ni = 0; ni < 4; ++ni)
                acc[mi][ni] = __builtin_amdgcn_mfma_f32_16x16x32_bf16(af[mi], bfv[ni], acc[mi][ni], 0, 0, 0);
    }
    const int rowBase = mT * TILE_M + wm, colBase = nT * TILE_N + wn;
    float bv[4];
    #pragma unroll
    for (int ni = 0; ni < 4; ++ni) bv[ni] = bias[colBase + ni * 16 + fr];
    #pragma unroll
    for (int mi = 0; mi < 4; ++mi)
        #pragma unroll
        for (int ni = 0; ni < 4; ++ni) {
            const int col = colBase + ni * 16 + fr;
            #pragma unroll
            for (int r = 0; r < 4; ++r) {
                const int row = rowBase + mi * 16 + quad * 4 + r;
                out[(size_t)row * kN + col] = fmaxf(acc[mi][ni][r] + bv[ni], 0.f);
            }
        }
}

extern "C" void kernel_launch(void* const* d_in, const int* in_sizes, int n_in,
                              void* d_out, int out_size, void* d_ws, size_t ws_size,
                              hipStream_t stream) {
    const float* words = (const float*)d_in[0];   // [8, 4096, 1024] f32
    const float* sents = (const float*)d_in[1];   // [8, 255, 1024]  f32
    const float* W     = (const float*)d_in[2];   // [1024, 2048]    f32
    const float* bias  = (const float*)d_in[3];   // [1024]          f32
    const int*   smap  = (const int*)d_in[4];     // [8, 4096]       i32
    float* out = (float*)d_out;                   // [8, 4096, 1024] f32

    if (ws_size >= WS_NEED) {
        uint8_t* ws = (uint8_t*)d_ws;
        uint4* wordsB = (uint4*)(ws + WS_WORDS);
        uint4* sentsB = (uint4*)(ws + WS_SENTS);
        uint4* WB     = (uint4*)(ws + WS_W);
        uint32_t* zp  = (uint32_t*)(ws + WS_ZP);
        cvt_prepass2<<<2048, 256, 0, stream>>>(
            (const float4*)words, (const float4*)sents, (const float4*)W,
            wordsB, sentsB, WB, zp);
        dim3 grid(kN / 256, kM / 256);            // (4, 128)
        wsib_gemm_v7<<<grid, 512, 0, stream>>>(
            (const uint8_t*)wordsB, (const uint8_t*)sentsB, (const uint8_t*)WB,
            bias, smap, (const uint8_t*)zp, out);
    } else {
        dim3 grid(kN / TILE_N, kM / TILE_M);
        wsib_gemm_fb<<<grid, 256, 0, stream>>>(words, sents, W, bias, smap, out);
    }
}